// Round 3
// baseline (119.297 us; speedup 1.0000x reference)
//
#include <hip/hip_runtime.h>

#define BATCH_N 65536
#define SEQ_N   128
#define DEPTH   16   // prefetch pipeline depth (registers: 16 x float2 = 32 VGPRs)

// Native clang vector type — accepted by __builtin_nontemporal_load/store
// (HIP's float2 is a class and is rejected).
typedef float v2f __attribute__((ext_vector_type(2)));

// One thread per batch element; 128-step sequential recurrence in registers.
// 1 wave/SIMD occupancy -> all latency hiding is the software pipeline:
// rotating 16-deep register buffer, first-use distance = 16 steps (~1600 cy)
// >> HBM latency (~900 cy). Nontemporal hints on the streamed in/out.
__global__ __launch_bounds__(256) void fsrs_kernel(
    const v2f* __restrict__ in,   // (SEQ, BATCH) of (t, rating)
    const float* __restrict__ w,  // 17 weights
    v2f*       __restrict__ out)  // (SEQ, BATCH) of (s, d) then (BATCH) final
{
    const int b = blockIdx.x * 256 + threadIdx.x;

    // Uniform weight loads (SGPRs).
    const float w0 = w[0], w1 = w[1], w2 = w[2], w3 = w[3];
    const float w4 = w[4], w5 = w[5], w6 = w[6], w7 = w[7];
    const float w9 = w[9], w11 = w[11], w12 = w[12], w13 = w[13];
    const float w15 = w[15], w16 = w[16];
    constexpr float LOG2E = 1.44269504088896340736f;
    const float w8l  = w[8]  * LOG2E;   // exp(w8)*s^-w9 = exp2(w8l - w9*log2(s))
    const float w10l = w[10] * LOG2E;
    const float w14l = w[14] * LOG2E;
    const float omw7   = 1.0f - w7;
    const float omw7w6 = omw7 * w6;
    const float dc0    = w7 * w4 + 3.0f * omw7w6; // nd = dc0 + omw7*d - omw7w6*rating

    const v2f* ip = in  + b;   // stride BATCH_N per timestep
    v2f*       op = out + b;

    float s = 0.01f, d = 1.0f;

    // One FSRS step (t >= 1): reads old (s,d), writes new (s,d).
    auto step = [&](v2f x) {
        const float tt     = x.x;
        const float rating = x.y;
        const float nineS = 9.0f * s;
        // 1 - r = t / (9s + t)
        const float rc  = __builtin_amdgcn_rcpf(nineS + tt);
        const float omr = tt * rc;
        // hard_penalty * easy_bonus: mutually exclusive -> one select chain
        const float hb = (rating == 2.0f) ? w15 : ((rating == 4.0f) ? w16 : 1.0f);

        const float log2s = __builtin_amdgcn_logf(s);
        const float ex    = __builtin_amdgcn_exp2f(__builtin_fmaf(-w9, log2s, w8l));
        const float e10   = __builtin_amdgcn_exp2f(omr * w10l);
        const float su    = ex * (11.0f - d) * (e10 - 1.0f) * hb;
        const float s_succ = __builtin_fmaf(su, s, s);   // s*(1+su)

        const float log2d  = __builtin_amdgcn_logf(d);
        const float powd   = __builtin_amdgcn_exp2f(-w12 * log2d);
        const float log2s1 = __builtin_amdgcn_logf(s + 1.0f);
        const float pows1  = __builtin_amdgcn_exp2f(w13 * log2s1);
        const float e14    = __builtin_amdgcn_exp2f(omr * w14l);
        const float s_fail = fminf(w11 * powd * (pows1 - 1.0f) * e14, s);

        const float ns = (rating > 1.0f) ? s_succ : s_fail;
        const float nd = __builtin_fmaf(omw7, d, __builtin_fmaf(-omw7w6, rating, dc0));
        d = fminf(fmaxf(nd, 1.0f), 10.0f);
        s = fminf(fmaxf(ns, 0.01f), 36500.0f);
    };

    auto st = [&](int idx) {
        v2f o; o.x = s; o.y = d;
        __builtin_nontemporal_store(o, &op[idx]);
    };

    // Prologue: load t = 0..15.
    v2f A[DEPTH];
#pragma unroll
    for (int i = 0; i < DEPTH; ++i)
        A[i] = __builtin_nontemporal_load(&ip[i * BATCH_N]);

    // Chunk 0: t=0 is the special first step; prefetch t = 16..31 as we go.
    {
        v2f x = A[0];
        A[0] = __builtin_nontemporal_load(&ip[DEPTH * BATCH_N]);
        const float rating = x.y;
        const float wsel = (rating < 2.5f) ? ((rating < 1.5f) ? w0 : w1)
                                           : ((rating < 3.5f) ? w2 : w3);
        const float ns = (rating >= 1.0f && rating <= 4.0f) ? wsel : 1.0f;
        const float nd = w4 - w5 * (rating - 3.0f);
        d = fminf(fmaxf(nd, 1.0f), 10.0f);
        s = fminf(fmaxf(ns, 0.01f), 36500.0f);
        st(0);
    }
#pragma unroll
    for (int i = 1; i < DEPTH; ++i) {
        v2f x = A[i];
        A[i] = __builtin_nontemporal_load(&ip[(DEPTH + i) * BATCH_N]);
        step(x);
        st(i * BATCH_N);
    }

    // Chunks 1..6: 16 steps each, prefetch chunk c+1 into the same slots.
#pragma unroll 1
    for (int c = 1; c < 7; ++c) {
#pragma unroll
        for (int i = 0; i < DEPTH; ++i) {
            v2f x = A[i];
            A[i] = __builtin_nontemporal_load(&ip[((c + 1) * DEPTH + i) * BATCH_N]);
            step(x);
            st((c * DEPTH + i) * BATCH_N);
        }
    }

    // Chunk 7: last 16 steps, no prefetch.
#pragma unroll
    for (int i = 0; i < DEPTH; ++i) {
        step(A[i]);
        st((7 * DEPTH + i) * BATCH_N);
    }

    // final_state, appended after the (SEQ, BATCH) outputs.
    {
        v2f o; o.x = s; o.y = d;
        op[SEQ_N * BATCH_N] = o;
    }
}

extern "C" void kernel_launch(void* const* d_in, const int* in_sizes, int n_in,
                              void* d_out, int out_size, void* d_ws, size_t ws_size,
                              hipStream_t stream) {
    const v2f*   in = (const v2f*)d_in[0];   // (128, 65536, 2) f32
    const float* w  = (const float*)d_in[1]; // (17,) f32
    v2f* out = (v2f*)d_out;                  // 128*65536 + 65536 float2
    fsrs_kernel<<<BATCH_N / 256, 256, 0, stream>>>(in, w, out);
}

// Round 4
// 116.029 us; speedup vs baseline: 1.0282x; 1.0282x over previous
//
#include <hip/hip_runtime.h>

#define BATCH_N 65536
#define SEQ_N   128
#define DEPTH   16

// Native clang vector type — accepted by __builtin_nontemporal_load/store.
typedef float v2f __attribute__((ext_vector_type(2)));

// One thread per batch element; 128-step sequential recurrence in registers.
// Double-buffered chunks of 16 rows. Critical ordering: each chunk issues all
// 16 loads for the NEXT chunk BEFORE any of this chunk's stores, so the
// in-order vmcnt queue never makes a load's completion wait behind a slow
// store (stores are younger than every load we wait on). Stores are
// nontemporal (write-once stream, keep out of L2/L3); loads are plain
// (input may be L2/L3-warm from the harness's restore copy).
__global__ __launch_bounds__(256) void fsrs_kernel(
    const v2f* __restrict__ in,   // (SEQ, BATCH) of (t, rating)
    const float* __restrict__ w,  // 17 weights
    v2f*       __restrict__ out)  // (SEQ, BATCH) of (s, d) then (BATCH) final
{
    const int b = blockIdx.x * 256 + threadIdx.x;

    // Uniform weight loads (SGPRs).
    const float w0 = w[0], w1 = w[1], w2 = w[2], w3 = w[3];
    const float w4 = w[4], w5 = w[5], w6 = w[6], w7 = w[7];
    const float w9 = w[9], w11 = w[11], w12 = w[12], w13 = w[13];
    const float w15 = w[15], w16 = w[16];
    constexpr float LOG2E = 1.44269504088896340736f;
    const float w8l  = w[8]  * LOG2E;   // exp(w8)*s^-w9 = exp2(w8l - w9*log2(s))
    const float w10l = w[10] * LOG2E;
    const float w14l = w[14] * LOG2E;
    const float omw7   = 1.0f - w7;
    const float omw7w6 = omw7 * w6;
    const float dc0    = w7 * w4 + 3.0f * omw7w6; // nd = dc0 + omw7*d - omw7w6*rating

    const v2f* ip = in  + b;   // stride BATCH_N per timestep
    v2f*       op = out + b;

    float s = 0.01f, d = 1.0f;

    // One FSRS step (t >= 1): reads old (s,d), writes new (s,d).
    auto step = [&](v2f x) {
        const float tt     = x.x;
        const float rating = x.y;
        const float nineS = 9.0f * s;
        // 1 - r = t / (9s + t)
        const float rc  = __builtin_amdgcn_rcpf(nineS + tt);
        const float omr = tt * rc;
        // hard_penalty * easy_bonus: mutually exclusive -> one select chain
        const float hb = (rating == 2.0f) ? w15 : ((rating == 4.0f) ? w16 : 1.0f);

        const float log2s = __builtin_amdgcn_logf(s);
        const float ex    = __builtin_amdgcn_exp2f(__builtin_fmaf(-w9, log2s, w8l));
        const float e10   = __builtin_amdgcn_exp2f(omr * w10l);
        const float su    = ex * (11.0f - d) * (e10 - 1.0f) * hb;
        const float s_succ = __builtin_fmaf(su, s, s);   // s*(1+su)

        const float log2d  = __builtin_amdgcn_logf(d);
        const float powd   = __builtin_amdgcn_exp2f(-w12 * log2d);
        const float log2s1 = __builtin_amdgcn_logf(s + 1.0f);
        const float pows1  = __builtin_amdgcn_exp2f(w13 * log2s1);
        const float e14    = __builtin_amdgcn_exp2f(omr * w14l);
        const float s_fail = fminf(w11 * powd * (pows1 - 1.0f) * e14, s);

        const float ns = (rating > 1.0f) ? s_succ : s_fail;
        const float nd = __builtin_fmaf(omw7, d, __builtin_fmaf(-omw7w6, rating, dc0));
        d = fminf(fmaxf(nd, 1.0f), 10.0f);
        s = fminf(fmaxf(ns, 0.01f), 36500.0f);
    };

    auto st = [&](int row) {
        v2f o; o.x = s; o.y = d;
        __builtin_nontemporal_store(o, &op[row * BATCH_N]);
    };

    v2f A[DEPTH], B[DEPTH];

    // Prologue: A = rows 0..15.
#pragma unroll
    for (int i = 0; i < DEPTH; ++i) A[i] = ip[i * BATCH_N];

    // Chunk 0 (rows 0..15) from A; first load B = rows 16..31.
#pragma unroll
    for (int i = 0; i < DEPTH; ++i) B[i] = ip[(DEPTH + i) * BATCH_N];
    {
        // t = 0: special first step.
        const float rating = A[0].y;
        const float wsel = (rating < 2.5f) ? ((rating < 1.5f) ? w0 : w1)
                                           : ((rating < 3.5f) ? w2 : w3);
        const float ns = (rating >= 1.0f && rating <= 4.0f) ? wsel : 1.0f;
        const float nd = w4 - w5 * (rating - 3.0f);
        d = fminf(fmaxf(nd, 1.0f), 10.0f);
        s = fminf(fmaxf(ns, 0.01f), 36500.0f);
        st(0);
    }
#pragma unroll
    for (int i = 1; i < DEPTH; ++i) { step(A[i]); st(i); }

    // Pairs of chunks: (1,2), (3,4), (5,6). Loads always precede the stores
    // of the chunk computed in the same half.
#pragma unroll 1
    for (int c = 0; c < 3; ++c) {
        const int ra = 32 + c * 32;       // rows to load into A
        // load A = rows ra..ra+15, then compute chunk (rows ra-16..ra-1) from B
#pragma unroll
        for (int i = 0; i < DEPTH; ++i) A[i] = ip[(ra + i) * BATCH_N];
#pragma unroll
        for (int i = 0; i < DEPTH; ++i) { step(B[i]); st(ra - DEPTH + i); }
        // load B = rows ra+16..ra+31, then compute chunk (rows ra..ra+15) from A
#pragma unroll
        for (int i = 0; i < DEPTH; ++i) B[i] = ip[(ra + DEPTH + i) * BATCH_N];
#pragma unroll
        for (int i = 0; i < DEPTH; ++i) { step(A[i]); st(ra + i); }
    }

    // Tail: chunk 7 (rows 112..127) from B, no more loads.
#pragma unroll
    for (int i = 0; i < DEPTH; ++i) { step(B[i]); st(112 + i); }

    // final_state, appended after the (SEQ, BATCH) outputs.
    {
        v2f o; o.x = s; o.y = d;
        op[SEQ_N * BATCH_N] = o;
    }
}

extern "C" void kernel_launch(void* const* d_in, const int* in_sizes, int n_in,
                              void* d_out, int out_size, void* d_ws, size_t ws_size,
                              hipStream_t stream) {
    const v2f*   in = (const v2f*)d_in[0];   // (128, 65536, 2) f32
    const float* w  = (const float*)d_in[1]; // (17,) f32
    v2f* out = (v2f*)d_out;                  // 128*65536 + 65536 float2
    fsrs_kernel<<<BATCH_N / 256, 256, 0, stream>>>(in, w, out);
}

// Round 5
// 114.890 us; speedup vs baseline: 1.0384x; 1.0099x over previous
//
#include <hip/hip_runtime.h>

#define BATCH_N 65536
#define SEQ_N   128

// Native clang vector type — accepted by __builtin_nontemporal_load/store.
typedef float v2f __attribute__((ext_vector_type(2)));

// One thread per batch element; 128-step sequential recurrence in registers.
// 1 wave/SIMD: no TLP, so (a) loads are double-buffered 16 rows ahead, and
// (b) everything derivable from ratings alone (the entire d-chain, the
// success multiplier (11-d)*hb, the failure multiplier w11*d^-w12) is
// precomputed in the load phase, off the s-chain's critical path. The
// success/failure flag is encoded in the sign of the merged multiplier M.
// Hot-phase step: 5 transcendentals (rcp, 2x log2, 2x exp2) + ~18 VALU.
__global__ __launch_bounds__(256) void fsrs_kernel(
    const v2f* __restrict__ in,   // (SEQ, BATCH) of (t, rating)
    const float* __restrict__ w,  // 17 weights
    v2f*       __restrict__ out)  // (SEQ, BATCH) of (s, d) then (BATCH) final
{
    const int b = blockIdx.x * 256 + threadIdx.x;

    const float w0 = w[0], w1 = w[1], w2 = w[2], w3 = w[3];
    const float w4 = w[4], w5 = w[5], w6 = w[6], w7 = w[7];
    const float w9 = w[9], w11 = w[11], w12 = w[12], w13 = w[13];
    const float w15 = w[15], w16 = w[16];
    constexpr float LOG2E = 1.44269504088896340736f;
    const float w8l  = w[8]  * LOG2E;   // exp(w8)*s^-w9 = exp2(w8l - w9*log2 s)
    const float w10l = w[10] * LOG2E;
    const float w14l = w[14] * LOG2E;
    const float omw7   = 1.0f - w7;
    const float omw7w6 = omw7 * w6;
    const float dc0    = w7 * w4 + 3.0f * omw7w6;

    const v2f* ip = in  + b;
    v2f*       op = out + b;

    float s = 0.01f;       // stability state
    float dcur = 1.0f;     // d lagging (output timing)
    float dpre = 1.0f;     // d running ahead (precompute timing)

    v2f rawA[16], rawB[16];
    float tA[16], dA[16], mA[16];   // t, new-d (output), merged multiplier
    float tB[16], dB[16], mB[16];

    auto loadC = [&](v2f* raw, int base) {
#pragma unroll
        for (int i = 0; i < 16; ++i) raw[i] = ip[(base + i) * BATCH_N];
    };

    // Precompute rows [lo,16) of a chunk. Uses/updates dpre (old d on entry
    // to each row). M[i] = success ? (11-d_old)*hb : -(w11*d_old^-w12);
    // sign(M) encodes the branch ((11-d)>=1>0 and w11*d^-w12>0 always).
    auto preC = [&](const v2f* raw, float* T, float* D, float* M, int lo) {
#pragma unroll
        for (int i = 0; i < 16; ++i) {
            if (i < lo) continue;
            const float tt = raw[i].x, rating = raw[i].y;
            const float hb = (rating == 2.0f) ? w15
                           : ((rating == 4.0f) ? w16 : 1.0f);
            const float eh = (11.0f - dpre) * hb;
            const float m2 = w11 * __builtin_amdgcn_exp2f(
                                 -w12 * __builtin_amdgcn_logf(dpre));
            M[i] = (rating > 1.0f) ? eh : -m2;
            const float nd = __builtin_fmaf(omw7, dpre,
                              __builtin_fmaf(-omw7w6, rating, dc0));
            dpre = fminf(fmaxf(nd, 1.0f), 10.0f);
            T[i] = tt;
            D[i] = dpre;
        }
    };

    // Hot phase: s-recurrence + store. All rating/d-dependent terms arrive
    // precomputed; only the s-chain runs here.
    auto stepC = [&](const float* T, const float* D, const float* M,
                     int base, int lo) {
#pragma unroll
        for (int i = 0; i < 16; ++i) {
            if (i < lo) continue;
            const float tt = T[i], ms = M[i];
            const bool  sel = ms > 0.0f;                    // success?
            const float q   = __builtin_fmaf(9.0f, s, tt);  // 9s + t
            const float omr = tt * __builtin_amdgcn_rcpf(q);// 1 - r
            const float e   = __builtin_amdgcn_exp2f(omr * (sel ? w10l : w14l));
            const float a1  = __builtin_fmaf(-w9, __builtin_amdgcn_logf(s), w8l);
            const float a2  = w13 * __builtin_amdgcn_logf(s + 1.0f);
            const float A   = __builtin_amdgcn_exp2f(sel ? a1 : a2);
            const float Af  = sel ? A          : (A - 1.0f);
            const float Ef  = sel ? (e - 1.0f) : e;
            const float m   = sel ? (ms * s)   : (-ms);
            const float P   = Af * Ef * m;
            const float ns  = sel ? (s + P) : fminf(P, s);
            s = fminf(fmaxf(ns, 0.01f), 36500.0f);
            dcur = D[i];
            v2f o; o.x = s; o.y = dcur;
            __builtin_nontemporal_store(o, &op[(base + i) * BATCH_N]);
        }
    };

    // ---- prologue: chunk k0 (rows 0..15) ----
    loadC(rawA, 0);
    {   // row 0: _first_step (both s0 and d0 come from rating only)
        const float rating = rawA[0].y;
        const float d0 = fminf(fmaxf(w4 - w5 * (rating - 3.0f), 1.0f), 10.0f);
        dpre = d0;
        tA[0] = rawA[0].x; dA[0] = d0; mA[0] = 1.0f;
    }
    preC(rawA, tA, dA, mA, 1);

    loadC(rawB, 16);
    {   // step row 0 (special): s0 from weight table
        const float rating = rawA[0].y;
        const float wsel = (rating < 2.5f) ? ((rating < 1.5f) ? w0 : w1)
                                           : ((rating < 3.5f) ? w2 : w3);
        const float ns = (rating >= 1.0f && rating <= 4.0f) ? wsel : 1.0f;
        s = fminf(fmaxf(ns, 0.01f), 36500.0f);
        dcur = dA[0];
        v2f o; o.x = s; o.y = dcur;
        __builtin_nontemporal_store(o, &op[0]);
    }
    stepC(tA, dA, mA, 0, 1);
    preC(rawB, tB, dB, mB, 0);

    // ---- main: chunk pairs (k2,k3), (k4,k5), (k6,k7) ----
#pragma unroll 1
    for (int c = 0; c < 3; ++c) {
        loadC(rawA, 32 * c + 32);
        stepC(tB, dB, mB, 32 * c + 16, 0);
        preC(rawA, tA, dA, mA, 0);

        loadC(rawB, 32 * c + 48);
        stepC(tA, dA, mA, 32 * c + 32, 0);
        preC(rawB, tB, dB, mB, 0);
    }

    // ---- tail: chunk k7 (rows 112..127) ----
    stepC(tB, dB, mB, 112, 0);

    // final_state, appended after the (SEQ, BATCH) outputs.
    {
        v2f o; o.x = s; o.y = dcur;
        op[SEQ_N * BATCH_N] = o;
    }
}

extern "C" void kernel_launch(void* const* d_in, const int* in_sizes, int n_in,
                              void* d_out, int out_size, void* d_ws, size_t ws_size,
                              hipStream_t stream) {
    const v2f*   in = (const v2f*)d_in[0];   // (128, 65536, 2) f32
    const float* w  = (const float*)d_in[1]; // (17,) f32
    v2f* out = (v2f*)d_out;                  // 128*65536 + 65536 float2
    fsrs_kernel<<<BATCH_N / 256, 256, 0, stream>>>(in, w, out);
}